// Round 1
// baseline (914.642 us; speedup 1.0000x reference)
//
#include <hip/hip_runtime.h>
#include <math.h>

// GCN: 3 x { h@W -> CSR-gather aggregate (sym-norm, self-loops) -> +b -> LN -> ReLU } -> mean-pool
// N=50000, E=800000, D=128, G=64 (G hardcoded; num_graphs input unused)

#define NDIM 128
#define LN_EPS 1e-5f
#define NGRAPH 64

// ---------------- graph build ----------------

__global__ __launch_bounds__(256) void k_deg(const int* __restrict__ dst, int* __restrict__ deg, int E) {
    int e = blockIdx.x * 256 + threadIdx.x;
    if (e < E) atomicAdd(&deg[dst[e]], 1);
}

// per-node: bump-allocate CSR range (wave-aggregated atomic), dinv = rsqrt(indeg+1), graph-size histogram
__global__ __launch_bounds__(256) void k_alloc(const int* __restrict__ deg, const int* __restrict__ batch,
                                               int* __restrict__ base, int* __restrict__ cursor,
                                               float* __restrict__ dinv, int* __restrict__ bump,
                                               int* __restrict__ cnt, int N) {
    int n = blockIdx.x * 256 + threadIdx.x;
    int lane = threadIdx.x & 63;
    int dg = (n < N) ? deg[n] : 0;
    int v = dg;
    #pragma unroll
    for (int o = 1; o < 64; o <<= 1) {
        int t = __shfl_up(v, o);
        if (lane >= o) v += t;
    }
    int total = __shfl(v, 63);          // wave sum
    int wb = 0;
    if (lane == 63) wb = atomicAdd(bump, total);
    wb = __shfl(wb, 63);
    if (n < N) {
        int b = wb + v - dg;            // exclusive prefix within wave
        base[n] = b;
        cursor[n] = b;
        dinv[n] = rsqrtf((float)(dg + 1));
        atomicAdd(&cnt[batch[n]], 1);
    }
}

__global__ __launch_bounds__(256) void k_fill(const int* __restrict__ src, const int* __restrict__ dst,
                                              int* __restrict__ cursor, int* __restrict__ csr, int E) {
    int e = blockIdx.x * 256 + threadIdx.x;
    if (e < E) {
        int p = atomicAdd(&cursor[dst[e]], 1);
        csr[p] = src[e];
    }
}

// ---------------- GEMM: C[N,128] = A[N,128] @ W[128,128] ----------------
// BM=64 rows/block, BK=32 k-tile, 256 threads: tx=col-group(0..31)->4 cols, ty=row-group(0..7)->8 rows

__global__ __launch_bounds__(256) void k_gemm(const float* __restrict__ A, const float* __restrict__ W,
                                              float* __restrict__ C, int N) {
    __shared__ float sA[64][33];     // +1 pad: rows 8 apart -> 2-way (free)
    __shared__ float sW[32][128];
    int tid = threadIdx.x;
    int tx = tid & 31, ty = tid >> 5;
    int row0 = blockIdx.x * 64;
    float acc[8][4];
    #pragma unroll
    for (int i = 0; i < 8; i++)
        #pragma unroll
        for (int j = 0; j < 4; j++) acc[i][j] = 0.f;

    for (int k0 = 0; k0 < 128; k0 += 32) {
        // stage A tile 64x32 (512 float4, 2/thread)
        #pragma unroll
        for (int j = 0; j < 2; j++) {
            int f = tid + j * 256;
            int r = f >> 3, c = (f & 7) * 4;
            int gr = row0 + r;
            float4 v = make_float4(0.f, 0.f, 0.f, 0.f);
            if (gr < N) v = *(const float4*)&A[gr * NDIM + k0 + c];
            sA[r][c] = v.x; sA[r][c + 1] = v.y; sA[r][c + 2] = v.z; sA[r][c + 3] = v.w;
        }
        // stage W tile 32x128 (1024 float4, 4/thread)
        #pragma unroll
        for (int j = 0; j < 4; j++) {
            int f = tid + j * 256;
            int r = f >> 5, c = (f & 31) * 4;
            *(float4*)&sW[r][c] = *(const float4*)&W[(k0 + r) * NDIM + c];
        }
        __syncthreads();
        #pragma unroll 8
        for (int kk = 0; kk < 32; kk++) {
            float4 wv = *(const float4*)&sW[kk][tx * 4];
            float a_[8];
            #pragma unroll
            for (int i = 0; i < 8; i++) a_[i] = sA[ty * 8 + i][kk];
            #pragma unroll
            for (int i = 0; i < 8; i++) {
                acc[i][0] += a_[i] * wv.x;
                acc[i][1] += a_[i] * wv.y;
                acc[i][2] += a_[i] * wv.z;
                acc[i][3] += a_[i] * wv.w;
            }
        }
        __syncthreads();
    }
    #pragma unroll
    for (int i = 0; i < 8; i++) {
        int gr = row0 + ty * 8 + i;
        if (gr < N)
            *(float4*)&C[gr * NDIM + tx * 4] = make_float4(acc[i][0], acc[i][1], acc[i][2], acc[i][3]);
    }
}

// ---------------- fused aggregate + bias + LayerNorm + ReLU ----------------
// one wave per node; lane owns dims (2*lane, 2*lane+1) as float2

__global__ __launch_bounds__(256) void k_agg(const float* __restrict__ hw, float* __restrict__ out,
                                             const float* __restrict__ dinv, const int* __restrict__ base,
                                             const int* __restrict__ deg, const int* __restrict__ csr,
                                             const float* __restrict__ bias, const float* __restrict__ gamma,
                                             const float* __restrict__ beta, int N) {
    int gtid = blockIdx.x * 256 + threadIdx.x;
    int n = gtid >> 6;
    int lane = threadIdx.x & 63;
    if (n >= N) return;

    const float2* hwv = (const float2*)hw;
    float dn = dinv[n];
    float2 sv = hwv[(size_t)n * 64 + lane];
    float a0 = dn * sv.x, a1 = dn * sv.y;   // self-loop term (x dn again below)

    int b0 = base[n], dg = deg[n];
    for (int i = 0; i < dg; i++) {
        int s = csr[b0 + i];                // wave-uniform -> broadcast
        float w = dinv[s];
        float2 hv = hwv[(size_t)s * 64 + lane];
        a0 += w * hv.x;
        a1 += w * hv.y;
    }
    a0 *= dn; a1 *= dn;

    float2 bv = ((const float2*)bias)[lane];
    a0 += bv.x; a1 += bv.y;

    float s1 = a0 + a1, s2 = a0 * a0 + a1 * a1;
    #pragma unroll
    for (int o = 1; o < 64; o <<= 1) {
        s1 += __shfl_xor(s1, o);
        s2 += __shfl_xor(s2, o);
    }
    float mu = s1 * (1.f / NDIM);
    float var = s2 * (1.f / NDIM) - mu * mu;
    float rs = rsqrtf(var + LN_EPS);

    float2 gv = ((const float2*)gamma)[lane];
    float2 be = ((const float2*)beta)[lane];
    float y0 = gv.x * (a0 - mu) * rs + be.x;
    float y1 = gv.y * (a1 - mu) * rs + be.y;
    y0 = fmaxf(y0, 0.f);
    y1 = fmaxf(y1, 0.f);
    ((float2*)out)[(size_t)n * 64 + lane] = make_float2(y0, y1);
}

// ---------------- mean pool ----------------
// 128 threads/block (thread = dim), 512 nodes/block; batch sorted -> flush on graph change

__global__ __launch_bounds__(128) void k_pool(const float* __restrict__ h, const int* __restrict__ batch,
                                              float* __restrict__ out, int N) {
    int d = threadIdx.x;
    int start = blockIdx.x * 512;
    if (start >= N) return;
    int end = min(start + 512, N);
    int cur = batch[start];
    float sum = 0.f;
    for (int n = start; n < end; n++) {
        int g = batch[n];
        if (g != cur) {
            atomicAdd(&out[cur * NDIM + d], sum);
            sum = 0.f;
            cur = g;
        }
        sum += h[(size_t)n * NDIM + d];
    }
    atomicAdd(&out[cur * NDIM + d], sum);
}

__global__ __launch_bounds__(256) void k_div(float* __restrict__ out, const int* __restrict__ cnt) {
    int i = blockIdx.x * 256 + threadIdx.x;
    if (i < NGRAPH * NDIM) {
        float c = (float)cnt[i >> 7];
        out[i] /= fmaxf(c, 1.f);
    }
}

// ---------------- launch ----------------

extern "C" void kernel_launch(void* const* d_in, const int* in_sizes, int n_in,
                              void* d_out, int out_size, void* d_ws, size_t ws_size,
                              hipStream_t stream) {
    const float* x      = (const float*)d_in[0];
    const int*   ei     = (const int*)d_in[1];
    const int*   batch  = (const int*)d_in[2];
    const float* Ws     = (const float*)d_in[3];
    const float* bs     = (const float*)d_in[4];
    const float* gammas = (const float*)d_in[5];
    const float* betas  = (const float*)d_in[6];
    float* out = (float*)d_out;

    int N = in_sizes[0] / NDIM;
    int E = in_sizes[1] / 2;
    const int* src = ei;
    const int* dst = ei + E;

    char* w = (char*)d_ws;
    auto alloc = [&](size_t bytes) { char* p = w; w += (bytes + 255) & ~(size_t)255; return p; };
    int*   deg    = (int*)alloc((size_t)N * 4);
    int*   base   = (int*)alloc((size_t)N * 4);
    int*   cursor = (int*)alloc((size_t)N * 4);
    float* dinv   = (float*)alloc((size_t)N * 4);
    int*   csr    = (int*)alloc((size_t)E * 4);
    int*   bump   = (int*)alloc(4 + NGRAPH * 4);   // bump counter + cnt[64], zeroed together
    int*   cnt    = bump + 1;
    float* bufA   = (float*)alloc((size_t)N * NDIM * 4);
    float* bufB   = (float*)alloc((size_t)N * NDIM * 4);

    hipMemsetAsync(deg, 0, (size_t)N * 4, stream);
    hipMemsetAsync(bump, 0, 4 + NGRAPH * 4, stream);
    hipMemsetAsync(out, 0, (size_t)NGRAPH * NDIM * 4, stream);

    int gE = (E + 255) / 256;
    int gN = (N + 255) / 256;
    k_deg<<<gE, 256, 0, stream>>>(dst, deg, E);
    k_alloc<<<gN, 256, 0, stream>>>(deg, batch, base, cursor, dinv, bump, cnt, N);
    k_fill<<<gE, 256, 0, stream>>>(src, dst, cursor, csr, E);

    int gGemm = (N + 63) / 64;
    int gAgg  = (N * 64 + 255) / 256;
    for (int l = 0; l < 3; l++) {
        const float* hin = (l == 0) ? x : bufA;
        k_gemm<<<gGemm, 256, 0, stream>>>(hin, Ws + (size_t)l * NDIM * NDIM, bufB, N);
        k_agg<<<gAgg, 256, 0, stream>>>(bufB, bufA, dinv, base, deg, csr,
                                        bs + l * NDIM, gammas + l * NDIM, betas + l * NDIM, N);
    }

    k_pool<<<(N + 511) / 512, 128, 0, stream>>>(bufA, batch, out, N);
    k_div<<<(NGRAPH * NDIM + 255) / 256, 256, 0, stream>>>(out, cnt);
}

// Round 2
// 510.008 us; speedup vs baseline: 1.7934x; 1.7934x over previous
//
#include <hip/hip_runtime.h>
#include <math.h>

// GCN: 3 x { h@W (*dinv epilogue) -> CSR-gather aggregate -> +b -> LN -> ReLU } -> mean-pool
// N=50000, E=800000, D=128, G=64

#define NDIM 128
#define LN_EPS 1e-5f
#define NGRAPH 64

// ---------------- graph build ----------------

__global__ __launch_bounds__(256) void k_deg(const int* __restrict__ dst, int* __restrict__ deg, int E) {
    int e = blockIdx.x * 256 + threadIdx.x;
    if (e < E) atomicAdd(&deg[dst[e]], 1);
}

// per-node: bump-allocate CSR range (wave-aggregated atomic), dinv = rsqrt(indeg+1),
// graph boundaries via sorted-batch boundary detection (NO atomics on cnt)
__global__ __launch_bounds__(256) void k_alloc(const int* __restrict__ deg, const int* __restrict__ batch,
                                               int* __restrict__ base, int* __restrict__ cursor,
                                               float* __restrict__ dinv, int* __restrict__ bump,
                                               int* __restrict__ gstart, int* __restrict__ gend, int N) {
    int n = blockIdx.x * 256 + threadIdx.x;
    int lane = threadIdx.x & 63;
    int dg = (n < N) ? deg[n] : 0;
    int v = dg;
    #pragma unroll
    for (int o = 1; o < 64; o <<= 1) {
        int t = __shfl_up(v, o);
        if (lane >= o) v += t;
    }
    int total = __shfl(v, 63);          // wave sum
    int wb = 0;
    if (lane == 63) wb = atomicAdd(bump, total);
    wb = __shfl(wb, 63);
    if (n < N) {
        int b = wb + v - dg;            // exclusive prefix within wave
        base[n] = b;
        cursor[n] = b;
        dinv[n] = rsqrtf((float)(dg + 1));
        int g = batch[n];
        if (n == 0 || batch[n - 1] != g) gstart[g] = n;
        if (n == N - 1 || batch[n + 1] != g) gend[g] = n + 1;
    }
}

__global__ __launch_bounds__(256) void k_fill(const int* __restrict__ src, const int* __restrict__ dst,
                                              int* __restrict__ cursor, int* __restrict__ csr, int E) {
    int e = blockIdx.x * 256 + threadIdx.x;
    if (e < E) {
        int p = atomicAdd(&cursor[dst[e]], 1);
        csr[p] = src[e];
    }
}

// ---------------- GEMM: C[N,128] = (A[N,128] @ W[128,128]) * dinv[row] ----------------
// BM=64 rows/block, BK=32 k-tile, 256 threads

__global__ __launch_bounds__(256) void k_gemm(const float* __restrict__ A, const float* __restrict__ W,
                                              float* __restrict__ C, const float* __restrict__ dinv, int N) {
    __shared__ float sA[64][33];
    __shared__ float sW[32][128];
    int tid = threadIdx.x;
    int tx = tid & 31, ty = tid >> 5;
    int row0 = blockIdx.x * 64;
    float acc[8][4];
    #pragma unroll
    for (int i = 0; i < 8; i++)
        #pragma unroll
        for (int j = 0; j < 4; j++) acc[i][j] = 0.f;

    for (int k0 = 0; k0 < 128; k0 += 32) {
        #pragma unroll
        for (int j = 0; j < 2; j++) {
            int f = tid + j * 256;
            int r = f >> 3, c = (f & 7) * 4;
            int gr = row0 + r;
            float4 v = make_float4(0.f, 0.f, 0.f, 0.f);
            if (gr < N) v = *(const float4*)&A[gr * NDIM + k0 + c];
            sA[r][c] = v.x; sA[r][c + 1] = v.y; sA[r][c + 2] = v.z; sA[r][c + 3] = v.w;
        }
        #pragma unroll
        for (int j = 0; j < 4; j++) {
            int f = tid + j * 256;
            int r = f >> 5, c = (f & 31) * 4;
            *(float4*)&sW[r][c] = *(const float4*)&W[(k0 + r) * NDIM + c];
        }
        __syncthreads();
        #pragma unroll 8
        for (int kk = 0; kk < 32; kk++) {
            float4 wv = *(const float4*)&sW[kk][tx * 4];
            float a_[8];
            #pragma unroll
            for (int i = 0; i < 8; i++) a_[i] = sA[ty * 8 + i][kk];
            #pragma unroll
            for (int i = 0; i < 8; i++) {
                acc[i][0] += a_[i] * wv.x;
                acc[i][1] += a_[i] * wv.y;
                acc[i][2] += a_[i] * wv.z;
                acc[i][3] += a_[i] * wv.w;
            }
        }
        __syncthreads();
    }
    #pragma unroll
    for (int i = 0; i < 8; i++) {
        int gr = row0 + ty * 8 + i;
        if (gr < N) {
            float dn = dinv[gr];
            *(float4*)&C[gr * NDIM + tx * 4] =
                make_float4(acc[i][0] * dn, acc[i][1] * dn, acc[i][2] * dn, acc[i][3] * dn);
        }
    }
}

// ---------------- fused aggregate + bias + LayerNorm + ReLU ----------------
// half-wave (32 lanes) per node; lane owns 4 dims as float4. hw is pre-scaled by dinv.

__global__ __launch_bounds__(256) void k_agg(const float* __restrict__ hw, float* __restrict__ out,
                                             const float* __restrict__ dinv, const int* __restrict__ base,
                                             const int* __restrict__ deg, const int* __restrict__ csr,
                                             const float* __restrict__ bias, const float* __restrict__ gamma,
                                             const float* __restrict__ beta, int N) {
    int gtid = blockIdx.x * 256 + threadIdx.x;
    int n = gtid >> 5;                  // 32 lanes per node
    int l4 = threadIdx.x & 31;
    if (n >= N) return;

    const float4* hwv = (const float4*)hw;
    float4 sv = hwv[(size_t)n * 32 + l4];   // self term: dinv[n]*hw[n] (pre-scaled)
    float a0 = sv.x, a1 = sv.y, a2 = sv.z, a3 = sv.w;

    int b0 = base[n], dg = deg[n];
    for (int i = 0; i < dg; i++) {
        int s = csr[b0 + i];
        float4 hv = hwv[(size_t)s * 32 + l4];   // dinv[s]*hw[s] (pre-scaled)
        a0 += hv.x; a1 += hv.y; a2 += hv.z; a3 += hv.w;
    }
    float dn = dinv[n];
    a0 *= dn; a1 *= dn; a2 *= dn; a3 *= dn;

    float4 bv = ((const float4*)bias)[l4];
    a0 += bv.x; a1 += bv.y; a2 += bv.z; a3 += bv.w;

    float s1 = a0 + a1 + a2 + a3;
    float s2 = a0 * a0 + a1 * a1 + a2 * a2 + a3 * a3;
    #pragma unroll
    for (int o = 1; o < 32; o <<= 1) {      // reduce within half-wave only
        s1 += __shfl_xor(s1, o);
        s2 += __shfl_xor(s2, o);
    }
    float mu = s1 * (1.f / NDIM);
    float var = s2 * (1.f / NDIM) - mu * mu;
    float rs = rsqrtf(var + LN_EPS);

    float4 gv = ((const float4*)gamma)[l4];
    float4 be = ((const float4*)beta)[l4];
    float y0 = fmaxf(gv.x * (a0 - mu) * rs + be.x, 0.f);
    float y1 = fmaxf(gv.y * (a1 - mu) * rs + be.y, 0.f);
    float y2 = fmaxf(gv.z * (a2 - mu) * rs + be.z, 0.f);
    float y3 = fmaxf(gv.w * (a3 - mu) * rs + be.w, 0.f);
    ((float4*)out)[(size_t)n * 32 + l4] = make_float4(y0, y1, y2, y3);
}

// ---------------- mean pool ----------------
// 128 threads/block (thread = dim), 64 nodes/block; batch sorted -> flush on graph change

__global__ __launch_bounds__(128) void k_pool(const float* __restrict__ h, const int* __restrict__ batch,
                                              float* __restrict__ out, int N) {
    int d = threadIdx.x;
    int start = blockIdx.x * 64;
    if (start >= N) return;
    int end = min(start + 64, N);
    int cur = batch[start];
    float sum = 0.f;
    for (int n = start; n < end; n++) {
        int g = batch[n];
        if (g != cur) {
            atomicAdd(&out[cur * NDIM + d], sum);
            sum = 0.f;
            cur = g;
        }
        sum += h[(size_t)n * NDIM + d];
    }
    atomicAdd(&out[cur * NDIM + d], sum);
}

__global__ __launch_bounds__(256) void k_div(float* __restrict__ out, const int* __restrict__ gstart,
                                             const int* __restrict__ gend) {
    int i = blockIdx.x * 256 + threadIdx.x;
    if (i < NGRAPH * NDIM) {
        int g = i >> 7;
        float c = (float)(gend[g] - gstart[g]);
        out[i] /= fmaxf(c, 1.f);
    }
}

// ---------------- launch ----------------

extern "C" void kernel_launch(void* const* d_in, const int* in_sizes, int n_in,
                              void* d_out, int out_size, void* d_ws, size_t ws_size,
                              hipStream_t stream) {
    const float* x      = (const float*)d_in[0];
    const int*   ei     = (const int*)d_in[1];
    const int*   batch  = (const int*)d_in[2];
    const float* Ws     = (const float*)d_in[3];
    const float* bs     = (const float*)d_in[4];
    const float* gammas = (const float*)d_in[5];
    const float* betas  = (const float*)d_in[6];
    float* out = (float*)d_out;

    int N = in_sizes[0] / NDIM;
    int E = in_sizes[1] / 2;
    const int* src = ei;
    const int* dst = ei + E;

    char* w = (char*)d_ws;
    auto alloc = [&](size_t bytes) { char* p = w; w += (bytes + 255) & ~(size_t)255; return p; };
    int*   deg    = (int*)alloc((size_t)N * 4);
    int*   base   = (int*)alloc((size_t)N * 4);
    int*   cursor = (int*)alloc((size_t)N * 4);
    float* dinv   = (float*)alloc((size_t)N * 4);
    int*   csr    = (int*)alloc((size_t)E * 4);
    int*   bump   = (int*)alloc((1 + 2 * NGRAPH) * 4);   // bump + gstart[64] + gend[64]
    int*   gstart = bump + 1;
    int*   gend   = gstart + NGRAPH;
    float* bufA   = (float*)alloc((size_t)N * NDIM * 4);
    float* bufB   = (float*)alloc((size_t)N * NDIM * 4);

    hipMemsetAsync(deg, 0, (size_t)N * 4, stream);
    hipMemsetAsync(bump, 0, (1 + 2 * NGRAPH) * 4, stream);
    hipMemsetAsync(out, 0, (size_t)NGRAPH * NDIM * 4, stream);

    int gE = (E + 255) / 256;
    int gN = (N + 255) / 256;
    k_deg<<<gE, 256, 0, stream>>>(dst, deg, E);
    k_alloc<<<gN, 256, 0, stream>>>(deg, batch, base, cursor, dinv, bump, gstart, gend, N);
    k_fill<<<gE, 256, 0, stream>>>(src, dst, cursor, csr, E);

    int gGemm = (N + 63) / 64;
    int gAgg  = (N * 32 + 255) / 256;
    for (int l = 0; l < 3; l++) {
        const float* hin = (l == 0) ? x : bufA;
        k_gemm<<<gGemm, 256, 0, stream>>>(hin, Ws + (size_t)l * NDIM * NDIM, bufB, dinv, N);
        k_agg<<<gAgg, 256, 0, stream>>>(bufB, bufA, dinv, base, deg, csr,
                                        bs + l * NDIM, gammas + l * NDIM, betas + l * NDIM, N);
    }

    k_pool<<<(N + 63) / 64, 128, 0, stream>>>(bufA, batch, out, N);
    k_div<<<(NGRAPH * NDIM + 255) / 256, 256, 0, stream>>>(out, gstart, gend);
}

// Round 3
// 420.714 us; speedup vs baseline: 2.1740x; 1.2122x over previous
//
#include <hip/hip_runtime.h>
#include <math.h>

// GCN: 3 x { h@W bf16-MFMA (*dinv epilogue, bf16 out) -> CSR-gather aggregate (bf16 reads)
//            -> +b -> LN -> ReLU (fp32 regs, bf16 store) } -> mean-pool
// N=50000, E=800000, D=128, G=64

#define NDIM 128
#define LN_EPS 1e-5f
#define NGRAPH 64

typedef __attribute__((ext_vector_type(8))) short short8;   // 8 bf16 = 4 VGPR (MFMA A/B frag)
typedef __attribute__((ext_vector_type(4))) float f32x4;    // MFMA C/D frag

__device__ __forceinline__ ushort f2bf(float f) {           // RNE fp32->bf16
    unsigned u = __float_as_uint(f);
    return (ushort)((u + 0x7FFF + ((u >> 16) & 1)) >> 16);
}
__device__ __forceinline__ float bf2f(ushort b) {
    return __uint_as_float(((unsigned)b) << 16);
}

// ---------------- graph build ----------------

__global__ __launch_bounds__(256) void k_deg(const int* __restrict__ dst, int* __restrict__ deg, int E) {
    int e = blockIdx.x * 256 + threadIdx.x;
    if (e < E) atomicAdd(&deg[dst[e]], 1);
}

__global__ __launch_bounds__(256) void k_alloc(const int* __restrict__ deg, const int* __restrict__ batch,
                                               int* __restrict__ base, int* __restrict__ cursor,
                                               float* __restrict__ dinv, int* __restrict__ bump,
                                               int* __restrict__ gstart, int* __restrict__ gend, int N) {
    int n = blockIdx.x * 256 + threadIdx.x;
    int lane = threadIdx.x & 63;
    int dg = (n < N) ? deg[n] : 0;
    int v = dg;
    #pragma unroll
    for (int o = 1; o < 64; o <<= 1) {
        int t = __shfl_up(v, o);
        if (lane >= o) v += t;
    }
    int total = __shfl(v, 63);
    int wb = 0;
    if (lane == 63) wb = atomicAdd(bump, total);
    wb = __shfl(wb, 63);
    if (n < N) {
        int b = wb + v - dg;
        base[n] = b;
        cursor[n] = b;
        dinv[n] = rsqrtf((float)(dg + 1));
        int g = batch[n];
        if (n == 0 || batch[n - 1] != g) gstart[g] = n;
        if (n == N - 1 || batch[n + 1] != g) gend[g] = n + 1;
    }
}

__global__ __launch_bounds__(256) void k_fill(const int* __restrict__ src, const int* __restrict__ dst,
                                              int* __restrict__ cursor, int* __restrict__ csr, int E) {
    int e = blockIdx.x * 256 + threadIdx.x;
    if (e < E) {
        int p = atomicAdd(&cursor[dst[e]], 1);
        csr[p] = src[e];
    }
}

// ---------------- weight prep: Wt[n][k] = W[k][n], bf16, XOR-swizzled in global ----------------
// swizzle: byte ^= ((n&7)<<4) -- matches gemm ds_read; LDS copy stays linear (rule: pre-swizzled global)

__global__ __launch_bounds__(256) void k_wt(const float* __restrict__ W, ushort* __restrict__ Wt) {
    int l = blockIdx.x;
    const float* w = W + (size_t)l * NDIM * NDIM;
    char* o = (char*)(Wt + (size_t)l * NDIM * NDIM);
    for (int idx = threadIdx.x; idx < NDIM * NDIM; idx += 256) {
        int k = idx >> 7, n = idx & 127;
        int byte = ((n * NDIM + k) * 2) ^ ((n & 7) << 4);
        *(ushort*)(o + byte) = f2bf(w[idx]);
    }
}

// ---------------- GEMM: C[N,128] = (A @ W) * dinv[row], bf16 MFMA ----------------
// 256 thr = 4 waves; block tile 128 rows x 128 cols; wave: 32 rows (M_rep=2 x 16), N_rep=8, K-steps=4
// A/B frag: lane holds 8 contiguous k-elems: row/col = lane&15, k = (lane>>4)*8 + e
// C/D frag: col = lane&15, row = (lane>>4)*4 + reg   [m89-verified]

template <bool AF32>
__global__ __launch_bounds__(256) void k_gemm(const void* __restrict__ Ap, const ushort* __restrict__ Wt,
                                              ushort* __restrict__ C, const float* __restrict__ dinv, int N) {
    __shared__ char sW[32768];
    int tid = threadIdx.x;
    {   // stage pre-swizzled Wt (32KB) linearly
        const float4* g = (const float4*)Wt;
        float4* s = (float4*)sW;
        #pragma unroll
        for (int i = 0; i < 8; i++) s[tid + 256 * i] = g[tid + 256 * i];
    }
    __syncthreads();

    int wave = tid >> 6, lane = tid & 63;
    int l15 = lane & 15, lhi = lane >> 4;
    int row0 = blockIdx.x * 128 + wave * 32;

    f32x4 acc[2][8];
    #pragma unroll
    for (int m = 0; m < 2; m++)
        #pragma unroll
        for (int n = 0; n < 8; n++) acc[m][n] = f32x4{0.f, 0.f, 0.f, 0.f};

    const float*  Af = (const float*)Ap;
    const ushort* Ab = (const ushort*)Ap;

    #pragma unroll
    for (int ks = 0; ks < 4; ks++) {
        int k = ks * 32 + lhi * 8;
        short8 a[2];
        #pragma unroll
        for (int m = 0; m < 2; m++) {
            int r = row0 + m * 16 + l15;
            if (r < N) {
                if (AF32) {
                    float4 v0 = *(const float4*)&Af[(size_t)r * NDIM + k];
                    float4 v1 = *(const float4*)&Af[(size_t)r * NDIM + k + 4];
                    short8 t;
                    t[0] = (short)f2bf(v0.x); t[1] = (short)f2bf(v0.y);
                    t[2] = (short)f2bf(v0.z); t[3] = (short)f2bf(v0.w);
                    t[4] = (short)f2bf(v1.x); t[5] = (short)f2bf(v1.y);
                    t[6] = (short)f2bf(v1.z); t[7] = (short)f2bf(v1.w);
                    a[m] = t;
                } else {
                    a[m] = *(const short8*)&Ab[(size_t)r * NDIM + k];
                }
            } else {
                a[m] = short8{};
            }
        }
        #pragma unroll
        for (int n = 0; n < 8; n++) {
            int nn = n * 16 + l15;
            int byte = (nn * 256 + k * 2) ^ ((nn & 7) << 4);
            short8 b = *(const short8*)(sW + byte);
            acc[0][n] = __builtin_amdgcn_mfma_f32_16x16x32_bf16(a[0], b, acc[0][n], 0, 0, 0);
            acc[1][n] = __builtin_amdgcn_mfma_f32_16x16x32_bf16(a[1], b, acc[1][n], 0, 0, 0);
        }
    }

    #pragma unroll
    for (int m = 0; m < 2; m++) {
        int rbase = row0 + m * 16 + lhi * 4;
        #pragma unroll
        for (int r = 0; r < 4; r++) {
            int row = rbase + r;
            if (row < N) {
                float dn = dinv[row];
                #pragma unroll
                for (int n = 0; n < 8; n++)
                    C[(size_t)row * NDIM + n * 16 + l15] = f2bf(acc[m][n][r] * dn);
            }
        }
    }
}

// ---------------- fused aggregate + bias + LayerNorm + ReLU (bf16 in/out) ----------------
// half-wave (32 lanes) per node; lane owns 4 dims (8B bf16 gather granule)

__global__ __launch_bounds__(256) void k_agg(const ushort* __restrict__ hw, ushort* __restrict__ out,
                                             const float* __restrict__ dinv, const int* __restrict__ base,
                                             const int* __restrict__ deg, const int* __restrict__ csr,
                                             const float* __restrict__ bias, const float* __restrict__ gamma,
                                             const float* __restrict__ beta, int N) {
    int gtid = blockIdx.x * 256 + threadIdx.x;
    int n = gtid >> 5;
    int l4 = threadIdx.x & 31;
    if (n >= N) return;

    const ushort4* hv = (const ushort4*)hw;
    ushort4 sv = hv[(size_t)n * 32 + l4];            // self term (pre-scaled by dinv)
    float a0 = bf2f(sv.x), a1 = bf2f(sv.y), a2 = bf2f(sv.z), a3 = bf2f(sv.w);

    int b0 = base[n], dg = deg[n];
    for (int i = 0; i < dg; i++) {
        int s = csr[b0 + i];                         // wave-uniform -> broadcast
        ushort4 t = hv[(size_t)s * 32 + l4];
        a0 += bf2f(t.x); a1 += bf2f(t.y); a2 += bf2f(t.z); a3 += bf2f(t.w);
    }
    float dn = dinv[n];
    a0 *= dn; a1 *= dn; a2 *= dn; a3 *= dn;

    float4 bv = ((const float4*)bias)[l4];
    a0 += bv.x; a1 += bv.y; a2 += bv.z; a3 += bv.w;

    float s1 = a0 + a1 + a2 + a3;
    float s2 = a0 * a0 + a1 * a1 + a2 * a2 + a3 * a3;
    #pragma unroll
    for (int o = 1; o < 32; o <<= 1) {
        s1 += __shfl_xor(s1, o);
        s2 += __shfl_xor(s2, o);
    }
    float mu = s1 * (1.f / NDIM);
    float var = s2 * (1.f / NDIM) - mu * mu;
    float rs = rsqrtf(var + LN_EPS);

    float4 gv = ((const float4*)gamma)[l4];
    float4 be = ((const float4*)beta)[l4];
    ushort4 y;
    y.x = f2bf(fmaxf(gv.x * (a0 - mu) * rs + be.x, 0.f));
    y.y = f2bf(fmaxf(gv.y * (a1 - mu) * rs + be.y, 0.f));
    y.z = f2bf(fmaxf(gv.z * (a2 - mu) * rs + be.z, 0.f));
    y.w = f2bf(fmaxf(gv.w * (a3 - mu) * rs + be.w, 0.f));
    ((ushort4*)out)[(size_t)n * 32 + l4] = y;
}

// ---------------- mean pool (bf16 in, fp32 out) ----------------

__global__ __launch_bounds__(128) void k_pool(const ushort* __restrict__ h, const int* __restrict__ batch,
                                              float* __restrict__ out, int N) {
    int d = threadIdx.x;
    int start = blockIdx.x * 64;
    if (start >= N) return;
    int end = min(start + 64, N);
    int cur = batch[start];
    float sum = 0.f;
    for (int n = start; n < end; n++) {
        int g = batch[n];
        if (g != cur) {
            atomicAdd(&out[cur * NDIM + d], sum);
            sum = 0.f;
            cur = g;
        }
        sum += bf2f(h[(size_t)n * NDIM + d]);
    }
    atomicAdd(&out[cur * NDIM + d], sum);
}

__global__ __launch_bounds__(256) void k_div(float* __restrict__ out, const int* __restrict__ gstart,
                                             const int* __restrict__ gend) {
    int i = blockIdx.x * 256 + threadIdx.x;
    if (i < NGRAPH * NDIM) {
        int g = i >> 7;
        float c = (float)(gend[g] - gstart[g]);
        out[i] /= fmaxf(c, 1.f);
    }
}

// ---------------- launch ----------------

extern "C" void kernel_launch(void* const* d_in, const int* in_sizes, int n_in,
                              void* d_out, int out_size, void* d_ws, size_t ws_size,
                              hipStream_t stream) {
    const float* x      = (const float*)d_in[0];
    const int*   ei     = (const int*)d_in[1];
    const int*   batch  = (const int*)d_in[2];
    const float* Ws     = (const float*)d_in[3];
    const float* bs     = (const float*)d_in[4];
    const float* gammas = (const float*)d_in[5];
    const float* betas  = (const float*)d_in[6];
    float* out = (float*)d_out;

    int N = in_sizes[0] / NDIM;
    int E = in_sizes[1] / 2;
    const int* src = ei;
    const int* dst = ei + E;

    char* w = (char*)d_ws;
    auto alloc = [&](size_t bytes) { char* p = w; w += (bytes + 255) & ~(size_t)255; return p; };
    int*    deg    = (int*)alloc((size_t)N * 4);
    int*    base   = (int*)alloc((size_t)N * 4);
    int*    cursor = (int*)alloc((size_t)N * 4);
    float*  dinv   = (float*)alloc((size_t)N * 4);
    int*    csr    = (int*)alloc((size_t)E * 4);
    int*    bump   = (int*)alloc((1 + 2 * NGRAPH) * 4);
    int*    gstart = bump + 1;
    int*    gend   = gstart + NGRAPH;
    ushort* Wt     = (ushort*)alloc((size_t)3 * NDIM * NDIM * 2);
    ushort* bufA   = (ushort*)alloc((size_t)N * NDIM * 2);   // h (bf16)
    ushort* bufB   = (ushort*)alloc((size_t)N * NDIM * 2);   // hw (bf16)

    hipMemsetAsync(deg, 0, (size_t)N * 4, stream);
    hipMemsetAsync(bump, 0, (1 + 2 * NGRAPH) * 4, stream);
    hipMemsetAsync(out, 0, (size_t)NGRAPH * NDIM * 4, stream);

    int gE = (E + 255) / 256;
    int gN = (N + 255) / 256;
    k_deg<<<gE, 256, 0, stream>>>(dst, deg, E);
    k_alloc<<<gN, 256, 0, stream>>>(deg, batch, base, cursor, dinv, bump, gstart, gend, N);
    k_fill<<<gE, 256, 0, stream>>>(src, dst, cursor, csr, E);
    k_wt<<<3, 256, 0, stream>>>(Ws, Wt);

    int gGemm = (N + 127) / 128;
    int gAgg  = (N * 32 + 255) / 256;
    for (int l = 0; l < 3; l++) {
        const ushort* wl = Wt + (size_t)l * NDIM * NDIM;
        if (l == 0)
            k_gemm<true><<<gGemm, 256, 0, stream>>>((const void*)x, wl, bufB, dinv, N);
        else
            k_gemm<false><<<gGemm, 256, 0, stream>>>((const void*)bufA, wl, bufB, dinv, N);
        k_agg<<<gAgg, 256, 0, stream>>>(bufB, bufA, dinv, base, deg, csr,
                                        bs + l * NDIM, gammas + l * NDIM, betas + l * NDIM, N);
    }

    k_pool<<<(N + 63) / 64, 128, 0, stream>>>(bufA, batch, out, N);
    k_div<<<(NGRAPH * NDIM + 255) / 256, 256, 0, stream>>>(out, gstart, gend);
}

// Round 4
// 359.567 us; speedup vs baseline: 2.5437x; 1.1701x over previous
//
#include <hip/hip_runtime.h>
#include <math.h>

// GCN: 3 x { h@W bf16-MFMA (*dinv epilogue, bf16 out) -> CSR-gather aggregate (bf16, MLP-4)
//            -> +b -> LN -> ReLU (fp32 regs, bf16 store) } -> mean-pool
// N=50000, E=800000, D=128, G=64

#define NDIM 128
#define LN_EPS 1e-5f
#define NGRAPH 64

typedef __attribute__((ext_vector_type(8))) short short8;   // 8 bf16 = 4 VGPR (MFMA A/B frag)
typedef __attribute__((ext_vector_type(4))) float f32x4;    // MFMA C/D frag

__device__ __forceinline__ ushort f2bf(float f) {           // RNE fp32->bf16
    unsigned u = __float_as_uint(f);
    return (ushort)((u + 0x7FFF + ((u >> 16) & 1)) >> 16);
}
__device__ __forceinline__ float bf2f(ushort b) {
    return __uint_as_float(((unsigned)b) << 16);
}

// ---------------- graph build ----------------

__global__ __launch_bounds__(256) void k_deg(const int* __restrict__ dst, int* __restrict__ deg, int E) {
    int e = blockIdx.x * 256 + threadIdx.x;
    if (e < E) atomicAdd(&deg[dst[e]], 1);
}

// per-node: bump-allocate CSR range PADDED to x4 (so int4 gather-index loads are aligned),
// dinv = rsqrt(deg+1), graph boundaries via sorted-batch detection
__global__ __launch_bounds__(256) void k_alloc(const int* __restrict__ deg, const int* __restrict__ batch,
                                               int* __restrict__ base, int* __restrict__ cursor,
                                               float* __restrict__ dinv, int* __restrict__ bump,
                                               int* __restrict__ gstart, int* __restrict__ gend, int N) {
    int n = blockIdx.x * 256 + threadIdx.x;
    int lane = threadIdx.x & 63;
    int dg = (n < N) ? deg[n] : 0;
    int dgp = (dg + 3) & ~3;            // padded allocation
    int v = dgp;
    #pragma unroll
    for (int o = 1; o < 64; o <<= 1) {
        int t = __shfl_up(v, o);
        if (lane >= o) v += t;
    }
    int total = __shfl(v, 63);
    int wb = 0;
    if (lane == 63) wb = atomicAdd(bump, total);
    wb = __shfl(wb, 63);
    if (n < N) {
        int b = wb + v - dgp;
        base[n] = b;
        cursor[n] = b;
        dinv[n] = rsqrtf((float)(dg + 1));
        int g = batch[n];
        if (n == 0 || batch[n - 1] != g) gstart[g] = n;
        if (n == N - 1 || batch[n + 1] != g) gend[g] = n + 1;
    }
}

__global__ __launch_bounds__(256) void k_fill(const int* __restrict__ src, const int* __restrict__ dst,
                                              int* __restrict__ cursor, int* __restrict__ csr, int E) {
    int e = blockIdx.x * 256 + threadIdx.x;
    if (e < E) {
        int p = atomicAdd(&cursor[dst[e]], 1);
        csr[p] = src[e];
    }
}

// ---------------- weight prep: Wt[n][k] = W[k][n], bf16, XOR-swizzled in global ----------------

__global__ __launch_bounds__(256) void k_wt(const float* __restrict__ W, ushort* __restrict__ Wt) {
    int l = blockIdx.x;
    const float* w = W + (size_t)l * NDIM * NDIM;
    char* o = (char*)(Wt + (size_t)l * NDIM * NDIM);
    for (int idx = threadIdx.x; idx < NDIM * NDIM; idx += 256) {
        int k = idx >> 7, n = idx & 127;
        int byte = ((n * NDIM + k) * 2) ^ ((n & 7) << 4);
        *(ushort*)(o + byte) = f2bf(w[idx]);
    }
}

// ---------------- GEMM: C[N,128] = (A @ W) * dinv[row], bf16 MFMA ----------------

template <bool AF32>
__global__ __launch_bounds__(256) void k_gemm(const void* __restrict__ Ap, const ushort* __restrict__ Wt,
                                              ushort* __restrict__ C, const float* __restrict__ dinv, int N) {
    __shared__ char sW[32768];
    int tid = threadIdx.x;
    {   // stage pre-swizzled Wt (32KB) linearly
        const float4* g = (const float4*)Wt;
        float4* s = (float4*)sW;
        #pragma unroll
        for (int i = 0; i < 8; i++) s[tid + 256 * i] = g[tid + 256 * i];
    }
    __syncthreads();

    int wave = tid >> 6, lane = tid & 63;
    int l15 = lane & 15, lhi = lane >> 4;
    int row0 = blockIdx.x * 128 + wave * 32;

    f32x4 acc[2][8];
    #pragma unroll
    for (int m = 0; m < 2; m++)
        #pragma unroll
        for (int n = 0; n < 8; n++) acc[m][n] = f32x4{0.f, 0.f, 0.f, 0.f};

    const float*  Af = (const float*)Ap;
    const ushort* Ab = (const ushort*)Ap;

    #pragma unroll
    for (int ks = 0; ks < 4; ks++) {
        int k = ks * 32 + lhi * 8;
        short8 a[2];
        #pragma unroll
        for (int m = 0; m < 2; m++) {
            int r = row0 + m * 16 + l15;
            if (r < N) {
                if (AF32) {
                    float4 v0 = *(const float4*)&Af[(size_t)r * NDIM + k];
                    float4 v1 = *(const float4*)&Af[(size_t)r * NDIM + k + 4];
                    short8 t;
                    t[0] = (short)f2bf(v0.x); t[1] = (short)f2bf(v0.y);
                    t[2] = (short)f2bf(v0.z); t[3] = (short)f2bf(v0.w);
                    t[4] = (short)f2bf(v1.x); t[5] = (short)f2bf(v1.y);
                    t[6] = (short)f2bf(v1.z); t[7] = (short)f2bf(v1.w);
                    a[m] = t;
                } else {
                    a[m] = *(const short8*)&Ab[(size_t)r * NDIM + k];
                }
            } else {
                a[m] = short8{};
            }
        }
        #pragma unroll
        for (int n = 0; n < 8; n++) {
            int nn = n * 16 + l15;
            int byte = (nn * 256 + k * 2) ^ ((nn & 7) << 4);
            short8 b = *(const short8*)(sW + byte);
            acc[0][n] = __builtin_amdgcn_mfma_f32_16x16x32_bf16(a[0], b, acc[0][n], 0, 0, 0);
            acc[1][n] = __builtin_amdgcn_mfma_f32_16x16x32_bf16(a[1], b, acc[1][n], 0, 0, 0);
        }
    }

    #pragma unroll
    for (int m = 0; m < 2; m++) {
        int rbase = row0 + m * 16 + lhi * 4;
        #pragma unroll
        for (int r = 0; r < 4; r++) {
            int row = rbase + r;
            if (row < N) {
                float dn = dinv[row];
                #pragma unroll
                for (int n = 0; n < 8; n++)
                    C[(size_t)row * NDIM + n * 16 + l15] = f2bf(acc[m][n][r] * dn);
            }
        }
    }
}

// ---------------- fused aggregate + bias + LayerNorm + ReLU (bf16 in/out) ----------------
// half-wave (32 lanes) per node; lane owns 4 dims. Pipelined unroll-4 gather: 4 rows in
// flight + next int4 of CSR indices prefetched -> 4x MLP vs serial loop.

__global__ __launch_bounds__(256) void k_agg(const ushort* __restrict__ hw, ushort* __restrict__ out,
                                             const float* __restrict__ dinv, const int* __restrict__ base,
                                             const int* __restrict__ deg, const int* __restrict__ csr,
                                             const float* __restrict__ bias, const float* __restrict__ gamma,
                                             const float* __restrict__ beta, int N) {
    int gtid = blockIdx.x * 256 + threadIdx.x;
    int n = gtid >> 5;
    int l4 = threadIdx.x & 31;
    if (n >= N) return;

    const ushort4* hv = (const ushort4*)hw;
    ushort4 sv = hv[(size_t)n * 32 + l4];            // self term (pre-scaled by dinv)
    float a0 = bf2f(sv.x), a1 = bf2f(sv.y), a2 = bf2f(sv.z), a3 = bf2f(sv.w);

    int b0 = base[n], dg = deg[n];
    int nfull = dg & ~3;
    int4 s4;
    if (nfull > 0) s4 = *(const int4*)&csr[b0];      // base padded to x4 -> aligned
    for (int i = 0; i < nfull; i += 4) {
        int4 cur = s4;
        if (i + 4 < nfull) s4 = *(const int4*)&csr[b0 + i + 4];   // prefetch next indices
        ushort4 t0 = hv[(size_t)cur.x * 32 + l4];
        ushort4 t1 = hv[(size_t)cur.y * 32 + l4];
        ushort4 t2 = hv[(size_t)cur.z * 32 + l4];
        ushort4 t3 = hv[(size_t)cur.w * 32 + l4];
        a0 += bf2f(t0.x) + bf2f(t1.x) + bf2f(t2.x) + bf2f(t3.x);
        a1 += bf2f(t0.y) + bf2f(t1.y) + bf2f(t2.y) + bf2f(t3.y);
        a2 += bf2f(t0.z) + bf2f(t1.z) + bf2f(t2.z) + bf2f(t3.z);
        a3 += bf2f(t0.w) + bf2f(t1.w) + bf2f(t2.w) + bf2f(t3.w);
    }
    for (int i = nfull; i < dg; i++) {
        int s = csr[b0 + i];
        ushort4 t = hv[(size_t)s * 32 + l4];
        a0 += bf2f(t.x); a1 += bf2f(t.y); a2 += bf2f(t.z); a3 += bf2f(t.w);
    }

    float dn = dinv[n];
    a0 *= dn; a1 *= dn; a2 *= dn; a3 *= dn;

    float4 bv = ((const float4*)bias)[l4];
    a0 += bv.x; a1 += bv.y; a2 += bv.z; a3 += bv.w;

    float s1 = a0 + a1 + a2 + a3;
    float s2 = a0 * a0 + a1 * a1 + a2 * a2 + a3 * a3;
    #pragma unroll
    for (int o = 1; o < 32; o <<= 1) {
        s1 += __shfl_xor(s1, o);
        s2 += __shfl_xor(s2, o);
    }
    float mu = s1 * (1.f / NDIM);
    float var = s2 * (1.f / NDIM) - mu * mu;
    float rs = rsqrtf(var + LN_EPS);

    float4 gv = ((const float4*)gamma)[l4];
    float4 be = ((const float4*)beta)[l4];
    ushort4 y;
    y.x = f2bf(fmaxf(gv.x * (a0 - mu) * rs + be.x, 0.f));
    y.y = f2bf(fmaxf(gv.y * (a1 - mu) * rs + be.y, 0.f));
    y.z = f2bf(fmaxf(gv.z * (a2 - mu) * rs + be.z, 0.f));
    y.w = f2bf(fmaxf(gv.w * (a3 - mu) * rs + be.w, 0.f));
    ((ushort4*)out)[(size_t)n * 32 + l4] = y;
}

// ---------------- mean pool (bf16 in, fp32 out) ----------------

__global__ __launch_bounds__(128) void k_pool(const ushort* __restrict__ h, const int* __restrict__ batch,
                                              float* __restrict__ out, int N) {
    int d = threadIdx.x;
    int start = blockIdx.x * 64;
    if (start >= N) return;
    int end = min(start + 64, N);
    int cur = batch[start];
    float sum = 0.f;
    for (int n = start; n < end; n++) {
        int g = batch[n];
        if (g != cur) {
            atomicAdd(&out[cur * NDIM + d], sum);
            sum = 0.f;
            cur = g;
        }
        sum += bf2f(h[(size_t)n * NDIM + d]);
    }
    atomicAdd(&out[cur * NDIM + d], sum);
}

__global__ __launch_bounds__(256) void k_div(float* __restrict__ out, const int* __restrict__ gstart,
                                             const int* __restrict__ gend) {
    int i = blockIdx.x * 256 + threadIdx.x;
    if (i < NGRAPH * NDIM) {
        int g = i >> 7;
        float c = (float)(gend[g] - gstart[g]);
        out[i] /= fmaxf(c, 1.f);
    }
}

// ---------------- launch ----------------

extern "C" void kernel_launch(void* const* d_in, const int* in_sizes, int n_in,
                              void* d_out, int out_size, void* d_ws, size_t ws_size,
                              hipStream_t stream) {
    const float* x      = (const float*)d_in[0];
    const int*   ei     = (const int*)d_in[1];
    const int*   batch  = (const int*)d_in[2];
    const float* Ws     = (const float*)d_in[3];
    const float* bs     = (const float*)d_in[4];
    const float* gammas = (const float*)d_in[5];
    const float* betas  = (const float*)d_in[6];
    float* out = (float*)d_out;

    int N = in_sizes[0] / NDIM;
    int E = in_sizes[1] / 2;
    const int* src = ei;
    const int* dst = ei + E;

    char* w = (char*)d_ws;
    auto alloc = [&](size_t bytes) { char* p = w; w += (bytes + 255) & ~(size_t)255; return p; };
    int*    deg    = (int*)alloc((size_t)N * 4);
    int*    base   = (int*)alloc((size_t)N * 4);
    int*    cursor = (int*)alloc((size_t)N * 4);
    float*  dinv   = (float*)alloc((size_t)N * 4);
    int*    csr    = (int*)alloc((size_t)(E + 3 * N + 64) * 4);   // padded-to-x4 per node
    int*    bump   = (int*)alloc((1 + 2 * NGRAPH) * 4);
    int*    gstart = bump + 1;
    int*    gend   = gstart + NGRAPH;
    ushort* Wt     = (ushort*)alloc((size_t)3 * NDIM * NDIM * 2);
    ushort* bufA   = (ushort*)alloc((size_t)N * NDIM * 2);   // h (bf16)
    ushort* bufB   = (ushort*)alloc((size_t)N * NDIM * 2);   // hw (bf16)

    hipMemsetAsync(deg, 0, (size_t)N * 4, stream);
    hipMemsetAsync(bump, 0, (1 + 2 * NGRAPH) * 4, stream);
    hipMemsetAsync(out, 0, (size_t)NGRAPH * NDIM * 4, stream);

    int gE = (E + 255) / 256;
    int gN = (N + 255) / 256;
    k_deg<<<gE, 256, 0, stream>>>(dst, deg, E);
    k_alloc<<<gN, 256, 0, stream>>>(deg, batch, base, cursor, dinv, bump, gstart, gend, N);
    k_fill<<<gE, 256, 0, stream>>>(src, dst, cursor, csr, E);
    k_wt<<<3, 256, 0, stream>>>(Ws, Wt);

    int gGemm = (N + 127) / 128;
    int gAgg  = (N * 32 + 255) / 256;
    for (int l = 0; l < 3; l++) {
        const ushort* wl = Wt + (size_t)l * NDIM * NDIM;
        if (l == 0)
            k_gemm<true><<<gGemm, 256, 0, stream>>>((const void*)x, wl, bufB, dinv, N);
        else
            k_gemm<false><<<gGemm, 256, 0, stream>>>((const void*)bufA, wl, bufB, dinv, N);
        k_agg<<<gAgg, 256, 0, stream>>>(bufB, bufA, dinv, base, deg, csr,
                                        bs + l * NDIM, gammas + l * NDIM, betas + l * NDIM, N);
    }

    k_pool<<<(N + 63) / 64, 128, 0, stream>>>(bufA, batch, out, N);
    k_div<<<(NGRAPH * NDIM + 255) / 256, 256, 0, stream>>>(out, gstart, gend);
}